// Round 1
// baseline (205.201 us; speedup 1.0000x reference)
//
#include <hip/hip_runtime.h>
#include <hip/hip_bf16.h>

typedef __attribute__((ext_vector_type(8))) short short8;
typedef __attribute__((ext_vector_type(4))) float f32x4;

#define NTOK   100000
#define H      150
#define KSEG   160        // padded per-matrix K
#define KTOT   640        // 4 * KSEG
#define NSTEP  20         // KTOT / 32
#define BM     64
#define NPAD   160        // padded output cols
#define LDP    40         // padded LDS row length (bf16 elems) -> 80B rows, 2-way bank alias (free)
#define OUTOFF (NTOK * H)

__device__ __forceinline__ unsigned short f2bf(float f) {
    unsigned int u = __builtin_bit_cast(unsigned int, f);
    u = (u + 0x7FFFu + ((u >> 16) & 1u)) >> 16;   // RNE
    return (unsigned short)u;
}

// ---------------------------------------------------------------------------
// Prepass: pack 4x [150,150] fp32 weights into Wb[c][k] bf16, c in [0,160),
// k in [0,640) stacked (w_in | w_out | u_in | u_out), zero-padded.
// Wb[c][k] = W_seg[k%160][c]  (transposed so GEMM B-frag reads are contiguous)
// ---------------------------------------------------------------------------
__global__ void prep_w(const float* __restrict__ w_in, const float* __restrict__ w_out,
                       const float* __restrict__ u_in, const float* __restrict__ u_out,
                       unsigned short* __restrict__ wb) {
    int idx = blockIdx.x * 256 + threadIdx.x;
    if (idx >= NPAD * KTOT) return;
    int c = idx / KTOT;
    int k = idx % KTOT;
    int seg = k / KSEG;
    int k2  = k % KSEG;
    float v = 0.0f;
    if (c < H && k2 < H) {
        const float* W = (seg == 0) ? w_in : (seg == 1) ? w_out : (seg == 2) ? u_in : u_out;
        v = W[k2 * H + c];
    }
    wb[idx] = f2bf(v);
}

// ---------------------------------------------------------------------------
// Main fused kernel: per block, 64 rows x 160 cols, K-loop over 640 (padded).
// 4 waves in 2x2 arrangement: each wave 32 rows x 80 cols = 2x5 fragments of
// 16x16, mfma_f32_16x16x32_bf16.
// ---------------------------------------------------------------------------
__global__ __launch_bounds__(256) void lstm_fused(
        const float* __restrict__ s_in, const float* __restrict__ s_out,
        const float* __restrict__ h_in, const float* __restrict__ h_out,
        const float* __restrict__ last_c, const unsigned short* __restrict__ wb,
        float* __restrict__ out) {
    __shared__ unsigned short Xl[BM][LDP];     // 5120 B
    __shared__ unsigned short Wl[NPAD][LDP];   // 12800 B

    const int t    = threadIdx.x;
    const int lane = t & 63;
    const int wid  = t >> 6;
    const int waveM = wid >> 1;   // 0..1
    const int waveN = wid & 1;    // 0..1
    const int row0 = blockIdx.x * BM;

    const float* Xseg[4] = {s_in, s_out, h_in, h_out};

    f32x4 acc[2][5];
#pragma unroll
    for (int m = 0; m < 2; m++)
#pragma unroll
        for (int n = 0; n < 5; n++) acc[m][n] = (f32x4){0.f, 0.f, 0.f, 0.f};

    // X staging assignment: thread -> (row, 8-elem k-chunk)
    const int srow = t >> 2;          // 0..63
    const int sq   = t & 3;           // 0..3
    const int grow = row0 + srow;
    const bool rowok = (grow < NTOK);

    const int lrow = lane & 15;       // fragment row/col within 16
    const int lko  = lane >> 4;       // k-group 0..3 (8 elems each)

    for (int ks = 0; ks < NSTEP; ks++) {
        const int k0  = ks * 32;
        const int seg = k0 / KSEG;              // uniform
        const int k2b = (k0 % KSEG) + sq * 8;   // within-segment k for this thread

        // ---- global loads into registers (before barrier) ----
        const float* Xp = Xseg[seg];
        float xv[8];
#pragma unroll
        for (int j = 0; j < 8; j += 2) {
            int k2 = k2b + j;
            float2 v = make_float2(0.f, 0.f);
            if (rowok && k2 < H) v = *(const float2*)&Xp[(long)grow * H + k2];
            xv[j] = v.x; xv[j + 1] = v.y;
        }
        short8 xr;
#pragma unroll
        for (int j = 0; j < 8; j++) xr[j] = (short)f2bf(xv[j]);

        // W chunks: 640 16B-chunks per step, threads take t, t+256, t+512
        short8 w0 = *(const short8*)&wb[((t       ) >> 2) * KTOT + k0 + ((t       ) & 3) * 8];
        short8 w1 = *(const short8*)&wb[((t + 256) >> 2) * KTOT + k0 + ((t + 256) & 3) * 8];
        short8 w2;
        const bool hasw2 = (t < 128);
        if (hasw2) w2 = *(const short8*)&wb[((t + 512) >> 2) * KTOT + k0 + ((t + 512) & 3) * 8];

        __syncthreads();   // previous iteration's LDS reads complete

        *(short8*)&Xl[srow][sq * 8] = xr;
        *(short8*)&Wl[(t       ) >> 2][((t       ) & 3) * 8] = w0;
        *(short8*)&Wl[(t + 256) >> 2][((t + 256) & 3) * 8] = w1;
        if (hasw2) *(short8*)&Wl[(t + 512) >> 2][((t + 512) & 3) * 8] = w2;

        __syncthreads();   // tile ready

        // ---- fragments + MFMA ----
        short8 af[2], bf[5];
#pragma unroll
        for (int m = 0; m < 2; m++)
            af[m] = *(const short8*)&Xl[waveM * 32 + m * 16 + lrow][lko * 8];
#pragma unroll
        for (int n = 0; n < 5; n++)
            bf[n] = *(const short8*)&Wl[waveN * 80 + n * 16 + lrow][lko * 8];
#pragma unroll
        for (int m = 0; m < 2; m++)
#pragma unroll
            for (int n = 0; n < 5; n++)
                acc[m][n] = __builtin_amdgcn_mfma_f32_16x16x32_bf16(af[m], bf[n], acc[m][n], 0, 0, 0);
    }

    // ---- fused epilogue: gate = sigmoid(pre); cell = g*lc + g*g; hid = g*tanh(cell)
#pragma unroll
    for (int m = 0; m < 2; m++) {
#pragma unroll
        for (int n = 0; n < 5; n++) {
            const int col = waveN * 80 + n * 16 + lrow;
            if (col >= H) continue;
#pragma unroll
            for (int r = 0; r < 4; r++) {
                const int row = row0 + waveM * 32 + m * 16 + lko * 4 + r;
                if (row >= NTOK) continue;
                float pre = acc[m][n][r];
                float g = 1.0f / (1.0f + __expf(-pre));
                float lc = last_c[(long)row * H + col];
                float cell = g * lc + g * g;
                float hid = g * tanhf(cell);
                out[(long)row * H + col] = hid;
                out[OUTOFF + (long)row * H + col] = cell;
            }
        }
    }
}

extern "C" void kernel_launch(void* const* d_in, const int* in_sizes, int n_in,
                              void* d_out, int out_size, void* d_ws, size_t ws_size,
                              hipStream_t stream) {
    const float* s_in   = (const float*)d_in[0];
    const float* s_out  = (const float*)d_in[1];
    const float* h_in   = (const float*)d_in[2];
    const float* h_out  = (const float*)d_in[3];
    const float* last_c = (const float*)d_in[4];
    const float* w_in   = (const float*)d_in[5];
    const float* w_out  = (const float*)d_in[6];
    const float* u_in   = (const float*)d_in[7];
    const float* u_out  = (const float*)d_in[8];

    unsigned short* wb = (unsigned short*)d_ws;   // 160*640*2 = 204800 B
    float* out = (float*)d_out;

    // Prepass: pack/transpose/convert weights
    prep_w<<<(NPAD * KTOT + 255) / 256, 256, 0, stream>>>(w_in, w_out, u_in, u_out, wb);

    // Main fused GEMM + LSTM pointwise
    const int nblocks = (NTOK + BM - 1) / BM;  // 1563
    lstm_fused<<<nblocks, 256, 0, stream>>>(s_in, s_out, h_in, h_out, last_c, wb, out);
}